// Round 2
// baseline (530.086 us; speedup 1.0000x reference)
//
#include <hip/hip_runtime.h>
#include <hip/hip_bf16.h>
#include <hip/hip_fp16.h>

#define N_NODES 10000
#define N_PAIRS 200000
#define NFEAT 384
#define FH 128
#define SPH 15

typedef __bf16 bf16x8 __attribute__((ext_vector_type(8)));
typedef _Float16 half8 __attribute__((ext_vector_type(8)));
typedef float f32x4 __attribute__((ext_vector_type(4)));

// ---------------- q/k GEMM (unchanged from round 1) ----------------
// q[n, h*128+g] = sum_f x[n, h*128+f] * Wq[h, g, f]   (and same for k)
// MFMA 16x16x32 bf16, outputs stored fp16 (halves gather traffic downstream).
__device__ inline bf16x8 cvt8(const float* __restrict__ p) {
    float4 lo = *(const float4*)p;
    float4 hi = *(const float4*)(p + 4);
    bf16x8 r;
    r[0] = (__bf16)lo.x; r[1] = (__bf16)lo.y; r[2] = (__bf16)lo.z; r[3] = (__bf16)lo.w;
    r[4] = (__bf16)hi.x; r[5] = (__bf16)hi.y; r[6] = (__bf16)hi.z; r[7] = (__bf16)hi.w;
    return r;
}

__global__ __launch_bounds__(256) void qk_gemm_kernel(
        const float* __restrict__ x,
        const float* __restrict__ Wq,
        const float* __restrict__ Wk,
        _Float16* __restrict__ q, _Float16* __restrict__ k) {
    const int head = blockIdx.y;
    const int node0 = blockIdx.x * 16;
    const int wave = threadIdx.x >> 6;
    const int lane = threadIdx.x & 63;
    const int mrow = lane & 15;
    const int quad = lane >> 4;
    const float* xrow = x + (size_t)(node0 + mrow) * NFEAT + head * FH + quad * 8;
    bf16x8 afrag[4];
#pragma unroll
    for (int t = 0; t < 4; ++t) afrag[t] = cvt8(xrow + t * 32);

    for (int task = wave; task < 16; task += 4) {
        const int mat = task & 1;
        const int g0 = (task >> 1) * 16;
        const float* Wrow =
            (mat ? Wk : Wq) + (size_t)head * FH * FH + (size_t)(g0 + mrow) * FH + quad * 8;
        f32x4 acc = {0.f, 0.f, 0.f, 0.f};
#pragma unroll
        for (int t = 0; t < 4; ++t) {
            bf16x8 b = cvt8(Wrow + t * 32);
            acc = __builtin_amdgcn_mfma_f32_16x16x32_bf16(afrag[t], b, acc, 0, 0, 0);
        }
        _Float16* dst = mat ? k : q;
        const int g = g0 + mrow;
#pragma unroll
        for (int r = 0; r < 4; ++r) {
            const int node = node0 + quad * 4 + r;
            dst[(size_t)node * NFEAT + head * FH + g] = (_Float16)acc[r];
        }
    }
}

// ---------------- CSR build: histogram -> scan -> scatter ----------------
__global__ __launch_bounds__(256) void count_kernel(const int* __restrict__ idx_i,
                                                    int* __restrict__ cnt) {
    for (int e = blockIdx.x * blockDim.x + threadIdx.x; e < N_PAIRS;
         e += gridDim.x * blockDim.x)
        atomicAdd(&cnt[idx_i[e]], 1);
}

// One block of 1024 threads; each thread scans 10 elements serially, then a
// Hillis-Steele scan over the 1024 partials in LDS. Writes exclusive starts
// twice (starts = stable copy, cursor = mutable for the scatter pass).
__global__ __launch_bounds__(1024) void scan_kernel(const int* __restrict__ cnt,
                                                    int* __restrict__ starts,
                                                    int* __restrict__ cursor) {
    __shared__ int lds[1024];
    const int tid = threadIdx.x;
    const int base = tid * 10;
    int pref[10];
    int s = 0;
#pragma unroll
    for (int t = 0; t < 10; ++t) {
        int v = (base + t < N_NODES) ? cnt[base + t] : 0;
        pref[t] = s;
        s += v;
    }
    lds[tid] = s;
    __syncthreads();
    for (int off = 1; off < 1024; off <<= 1) {
        int v = (tid >= off) ? lds[tid - off] : 0;
        __syncthreads();
        lds[tid] += v;
        __syncthreads();
    }
    const int excl = tid ? lds[tid - 1] : 0;
#pragma unroll
    for (int t = 0; t < 10; ++t) {
        if (base + t < N_NODES) {
            const int v = excl + pref[t];
            starts[base + t] = v;
            cursor[base + t] = v;
        }
    }
}

__global__ __launch_bounds__(256) void scatter_kernel(const int* __restrict__ idx_i,
                                                      int* __restrict__ cursor,
                                                      int* __restrict__ perm) {
    for (int e = blockIdx.x * blockDim.x + threadIdx.x; e < N_PAIRS;
         e += gridDim.x * blockDim.x) {
        const int i = idx_i[e];
        const int pos = atomicAdd(&cursor[i], 1);
        perm[pos] = e;
    }
}

// ---------------- node-centric scatter phase ----------------
// One wave per node. q row loaded ONCE into registers (vs once per pair).
// 16 lanes per pair, 4 pairs in flight per wave. Accumulates out[node,:] in
// registers -> single non-atomic store, no output memset needed.
__global__ __launch_bounds__(256) void node_kernel(
        const _Float16* __restrict__ q, const _Float16* __restrict__ kk,
        const float* __restrict__ w_ij, const float* __restrict__ sph,
        const int* __restrict__ perm, const int* __restrict__ starts,
        const int* __restrict__ cnt, const int* __restrict__ idx_j,
        const float* __restrict__ phi_r, const float* __restrict__ phi_chi,
        float* __restrict__ out) {
    const int lane = threadIdx.x & 63;
    const int sub = lane & 15;   // lane within pair-group
    const int grp = lane >> 4;   // which of 4 pairs in flight
    const int node = blockIdx.x * (blockDim.x >> 6) + (threadIdx.x >> 6);
    if (node >= N_NODES) return;

    const int start = starts[node];
    const int end = start + cnt[node];

    // q row for this node, sub's 8-feat slice per head (reused for all pairs)
    half8 qv[3];
#pragma unroll
    for (int h = 0; h < 3; ++h)
        qv[h] = *(const half8*)(q + (size_t)node * NFEAT + h * FH + sub * 8);

    float acc = 0.f;  // lane sub (<15) holds out[node, sub] partial for its group

    for (int p = start + grp; p < end; p += 4) {
        const int e = perm[p];
        const int j = idx_j[e];
        const _Float16* kr = kk + (size_t)j * NFEAT;
        const float* wr = w_ij + (size_t)e * NFEAT;
        float dot[3];
#pragma unroll
        for (int h = 0; h < 3; ++h) {
            const int f = h * FH + sub * 8;
            half8 kv = *(const half8*)(kr + f);
            f32x4 wa = __builtin_nontemporal_load((const f32x4*)(wr + f));
            f32x4 wb = __builtin_nontemporal_load((const f32x4*)(wr + f + 4));
            float d = 0.f;
#pragma unroll
            for (int u = 0; u < 4; ++u) {
                d = fmaf((float)qv[h][u] * wa[u], (float)kv[u], d);
                d = fmaf((float)qv[h][u + 4] * wb[u], (float)kv[u + 4], d);
            }
#pragma unroll
            for (int off = 8; off; off >>= 1) d += __shfl_xor(d, off, 16);
            dot[h] = d;
        }
        const float pr = __builtin_nontemporal_load(phi_r + e);
        const float pc = __builtin_nontemporal_load(phi_chi + e);
        const float scale = (pr + pc) * 0.088388347648318447f;  // 1/sqrt(128)
        if (sub < SPH) {
            const int h = (sub < 3) ? 0 : (sub < 8 ? 1 : 2);
            const float sv = __builtin_nontemporal_load(sph + (size_t)e * SPH + sub);
            acc = fmaf(dot[h] * scale, sv, acc);
        }
    }

    // sum the 4 pair-groups' partials (lanes sub, sub+16, sub+32, sub+48)
    acc += __shfl_xor(acc, 16);
    acc += __shfl_xor(acc, 32);
    if (grp == 0 && sub < SPH) out[(size_t)node * SPH + sub] = acc;
}

extern "C" void kernel_launch(void* const* d_in, const int* in_sizes, int n_in,
                              void* d_out, int out_size, void* d_ws, size_t ws_size,
                              hipStream_t stream) {
    // inputs: 0 chi (unused), 1 sph_ij, 2 x, 3 w_ij, 4 idx_i, 5 phi_r_cut,
    //         6 phi_chi_cut, 7 idx_j, 8 Wq, 9 Wk
    const float* sph     = (const float*)d_in[1];
    const float* x       = (const float*)d_in[2];
    const float* w_ij    = (const float*)d_in[3];
    const int*   idx_i   = (const int*)d_in[4];
    const float* phi_r   = (const float*)d_in[5];
    const float* phi_chi = (const float*)d_in[6];
    const int*   idx_j   = (const int*)d_in[7];
    const float* Wq      = (const float*)d_in[8];
    const float* Wk      = (const float*)d_in[9];
    float* out = (float*)d_out;

    // workspace layout (bytes):
    //   q fp16      @ 0          (7,680,000)
    //   k fp16      @ 7,680,000  (7,680,000)
    //   cnt         @ 15,360,000 (40,000)
    //   starts      @ 15,400,000 (40,000)
    //   cursor      @ 15,440,000 (40,000)
    //   perm        @ 15,480,000 (800,000)
    char* ws = (char*)d_ws;
    _Float16* qws = (_Float16*)ws;
    _Float16* kws = (_Float16*)(ws + 7680000);
    int* cnt    = (int*)(ws + 15360000);
    int* starts = (int*)(ws + 15400000);
    int* cursor = (int*)(ws + 15440000);
    int* perm   = (int*)(ws + 15480000);

    hipMemsetAsync(cnt, 0, N_NODES * sizeof(int), stream);
    count_kernel<<<256, 256, 0, stream>>>(idx_i, cnt);
    scan_kernel<<<1, 1024, 0, stream>>>(cnt, starts, cursor);
    scatter_kernel<<<256, 256, 0, stream>>>(idx_i, cursor, perm);

    qk_gemm_kernel<<<dim3(N_NODES / 16, 3), 256, 0, stream>>>(x, Wq, Wk, qws, kws);

    node_kernel<<<(N_NODES + 3) / 4, 256, 0, stream>>>(
        qws, kws, w_ij, sph, perm, starts, cnt, idx_j, phi_r, phi_chi, out);
}

// Round 3
// 482.462 us; speedup vs baseline: 1.0987x; 1.0987x over previous
//
#include <hip/hip_runtime.h>
#include <hip/hip_bf16.h>
#include <hip/hip_fp16.h>

#define N_NODES 10000
#define N_PAIRS 200000
#define NFEAT 384
#define FH 128
#define SPH 15

typedef __bf16 bf16x8 __attribute__((ext_vector_type(8)));
typedef _Float16 half8 __attribute__((ext_vector_type(8)));
typedef float f32x4 __attribute__((ext_vector_type(4)));

// ---------------- q/k GEMM ----------------
// q[n, h*128+g] = sum_f x[n, h*128+f] * Wq[h, g, f]   (and same for k)
// MFMA 16x16x32 bf16, outputs stored fp16 (halves gather traffic downstream).
__device__ inline bf16x8 cvt8(const float* __restrict__ p) {
    float4 lo = *(const float4*)p;
    float4 hi = *(const float4*)(p + 4);
    bf16x8 r;
    r[0] = (__bf16)lo.x; r[1] = (__bf16)lo.y; r[2] = (__bf16)lo.z; r[3] = (__bf16)lo.w;
    r[4] = (__bf16)hi.x; r[5] = (__bf16)hi.y; r[6] = (__bf16)hi.z; r[7] = (__bf16)hi.w;
    return r;
}

__global__ __launch_bounds__(256) void qk_gemm_kernel(
        const float* __restrict__ x,
        const float* __restrict__ Wq,
        const float* __restrict__ Wk,
        _Float16* __restrict__ q, _Float16* __restrict__ k) {
    const int head = blockIdx.y;
    const int node0 = blockIdx.x * 16;
    const int wave = threadIdx.x >> 6;
    const int lane = threadIdx.x & 63;
    const int mrow = lane & 15;
    const int quad = lane >> 4;
    const float* xrow = x + (size_t)(node0 + mrow) * NFEAT + head * FH + quad * 8;
    bf16x8 afrag[4];
#pragma unroll
    for (int t = 0; t < 4; ++t) afrag[t] = cvt8(xrow + t * 32);

    for (int task = wave; task < 16; task += 4) {
        const int mat = task & 1;
        const int g0 = (task >> 1) * 16;
        const float* Wrow =
            (mat ? Wk : Wq) + (size_t)head * FH * FH + (size_t)(g0 + mrow) * FH + quad * 8;
        f32x4 acc = {0.f, 0.f, 0.f, 0.f};
#pragma unroll
        for (int t = 0; t < 4; ++t) {
            bf16x8 b = cvt8(Wrow + t * 32);
            acc = __builtin_amdgcn_mfma_f32_16x16x32_bf16(afrag[t], b, acc, 0, 0, 0);
        }
        _Float16* dst = mat ? k : q;
        const int g = g0 + mrow;
#pragma unroll
        for (int r = 0; r < 4; ++r) {
            const int node = node0 + quad * 4 + r;
            dst[(size_t)node * NFEAT + head * FH + g] = (_Float16)acc[r];
        }
    }
}

// ---------------- pair phase (edge-parallel, round-1 structure) ----------------
// 16-lane-row sum via DPP row_ror (VALU pipe, ~4-8 cyc/step) instead of
// ds_swizzle-based __shfl_xor (DS pipe, ~30-40 cyc/step). 16-lane groups are
// exactly gfx9 DPP "rows", so row_ror stays within the group.
template <int CTRL>
__device__ __forceinline__ float dpp_add(float v) {
    int r = __builtin_amdgcn_update_dpp(0, __builtin_bit_cast(int, v), CTRL,
                                        0xf, 0xf, true);
    return v + __builtin_bit_cast(float, r);
}
__device__ __forceinline__ float row16_sum(float v) {
    v = dpp_add<0x128>(v);  // += ror 8
    v = dpp_add<0x124>(v);  // += ror 4
    v = dpp_add<0x122>(v);  // += ror 2
    v = dpp_add<0x121>(v);  // += ror 1
    return v;
}

// 4 pairs per wave, 16 lanes per pair. Lane `sub` owns 8 feats/head.
// alpha[h] = (sum_f q[i,h,f]*w[e,h,f]*k[j,h,f]) / sqrt(128) * (phi_r[e]+phi_chi[e])
// then subs 0..14 of each group scatter alpha_rep[c]*sph[e,c] into out[i,c].
__global__ __launch_bounds__(256) void pair_kernel(
        const _Float16* __restrict__ q, const _Float16* __restrict__ kk,
        const float* __restrict__ w_ij, const float* __restrict__ sph,
        const int* __restrict__ idx_i, const int* __restrict__ idx_j,
        const float* __restrict__ phi_r, const float* __restrict__ phi_chi,
        float* __restrict__ out) {
    const int lane = threadIdx.x & 63;
    const int sub = lane & 15;   // lane within pair-group
    const int grp = lane >> 4;   // which of 4 pairs in this wave
    const int wid = blockIdx.x * (blockDim.x >> 6) + (threadIdx.x >> 6);
    const int nw = gridDim.x * (blockDim.x >> 6);
    for (int base = wid * 4; base < N_PAIRS; base += nw * 4) {
        const int e = base + grp;
        if (e < N_PAIRS) {
            const int i = __builtin_nontemporal_load(idx_i + e);
            const int j = __builtin_nontemporal_load(idx_j + e);
            // issue the streamed scalars early so they're in flight during FMAs
            const float pr = __builtin_nontemporal_load(phi_r + e);
            const float pc = __builtin_nontemporal_load(phi_chi + e);
            float sv = 0.f;
            if (sub < SPH)
                sv = __builtin_nontemporal_load(sph + (size_t)e * SPH + sub);
            const _Float16* qr = q + (size_t)i * NFEAT;
            const _Float16* kr = kk + (size_t)j * NFEAT;
            const float* wr = w_ij + (size_t)e * NFEAT;
            float dot[3];
#pragma unroll
            for (int h = 0; h < 3; ++h) {
                const int f = h * FH + sub * 8;
                half8 qv = *(const half8*)(qr + f);
                half8 kv = *(const half8*)(kr + f);
                f32x4 wa = __builtin_nontemporal_load((const f32x4*)(wr + f));
                f32x4 wb = __builtin_nontemporal_load((const f32x4*)(wr + f + 4));
                float d = 0.f;
#pragma unroll
                for (int u = 0; u < 4; ++u) {
                    d = fmaf((float)qv[u] * wa[u], (float)kv[u], d);
                    d = fmaf((float)qv[u + 4] * wb[u], (float)kv[u + 4], d);
                }
                dot[h] = row16_sum(d);
            }
            const float scale = (pr + pc) * 0.088388347648318447f;  // 1/sqrt(128)
            if (sub < SPH) {
                const int h = (sub < 3) ? 0 : (sub < 8 ? 1 : 2);
                const float val = dot[h] * scale * sv;
                unsafeAtomicAdd(&out[(size_t)i * SPH + sub], val);
            }
        }
    }
}

extern "C" void kernel_launch(void* const* d_in, const int* in_sizes, int n_in,
                              void* d_out, int out_size, void* d_ws, size_t ws_size,
                              hipStream_t stream) {
    // inputs: 0 chi (unused), 1 sph_ij, 2 x, 3 w_ij, 4 idx_i, 5 phi_r_cut,
    //         6 phi_chi_cut, 7 idx_j, 8 Wq, 9 Wk
    const float* sph     = (const float*)d_in[1];
    const float* x       = (const float*)d_in[2];
    const float* w_ij    = (const float*)d_in[3];
    const int*   idx_i   = (const int*)d_in[4];
    const float* phi_r   = (const float*)d_in[5];
    const float* phi_chi = (const float*)d_in[6];
    const int*   idx_j   = (const int*)d_in[7];
    const float* Wq      = (const float*)d_in[8];
    const float* Wk      = (const float*)d_in[9];
    float* out = (float*)d_out;

    // workspace layout: q (7.68 MB fp16) + k (7.68 MB fp16)
    char* ws = (char*)d_ws;
    _Float16* qws = (_Float16*)ws;
    _Float16* kws = (_Float16*)(ws + 7680000);

    hipMemsetAsync(d_out, 0, (size_t)out_size * sizeof(float), stream);

    qk_gemm_kernel<<<dim3(N_NODES / 16, 3), 256, 0, stream>>>(x, Wq, Wk, qws, kws);

    pair_kernel<<<2048, 256, 0, stream>>>(qws, kws, w_ij, sph, idx_i, idx_j,
                                          phi_r, phi_chi, out);
}